// Round 8
// baseline (325.094 us; speedup 1.0000x reference)
//
#include <hip/hip_runtime.h>
#include <hip/hip_bf16.h>

#define B_  16
#define C_  64
#define H_  128
#define W_  128
#define HW_ (H_*W_)
#define E_  8

// ws layout (float offsets)
#define WS_LOGITS 0       // 128 floats (atomic-accumulated)
#define WS_SEL    128     // 32 ints: e1[16] then e2[16]

// ---- sentinel: encode a failed host-side assertion in the absmax ----
__global__ void k_sentinel(float* out, float v){
    if (blockIdx.x == 0 && threadIdx.x == 0) out[0] = v;
}

// ================= k1p: router conv + fused gating dot =================
// 16x64 pixel tile, 8 channel groups of 8 channels (2048 blocks).
// ALL 8 channels staged at once (one barrier), offsets precomputed once.
// After the conv, each thread dots its 4 r-values with wg[px,0..7];
// block-reduced 8 partial logits are atomicAdd'ed into ws logits.
#define R_TH 16
#define R_TW 64
#define R_HH (R_TH+6)    // 22
#define R_HW (R_TW+6)    // 70
#define R_LS 72          // LDS row stride: mult of 4 (aligned b128) , mod32=8
#define R_PL (R_HH*R_LS) // 1584 plane stride
#define R_HN (R_HH*R_HW) // 1540
#define RG_CH 8          // channels per group
#define R_SL  7          // staging slots/thread (1540/256 -> 7)

__global__ __launch_bounds__(256) void k1p(const float* __restrict__ x,
                                           const float* __restrict__ rw,
                                           const float* __restrict__ rb,
                                           const float* __restrict__ wg,
                                           float* __restrict__ logits){
    __shared__ __align__(16) float tile[RG_CH*R_PL];   // 12672 f = 50.7 KB
    __shared__ float pred[4][E_];

    int id = blockIdx.x;
    int g   = id & 7; id >>= 3;      // channel group (8)
    int txt = id & 1; id >>= 1;      // col half
    int tyt = id & 7; id >>= 3;      // 16-row band
    int b   = id;                    // 16
    int row0 = tyt*R_TH, col0 = txt*R_TW;
    int tx = threadIdx.x & 15, ty = threadIdx.x >> 4;
    int row  = row0 + ty;
    int colb = col0 + 4*tx;

    const float* xg  = x  + ((size_t)(b*C_) + g*RG_CH)*HW_;
    const float* wgr = rw + g*RG_CH*49;

    // ---- precompute staging offsets (spatial pattern, shared by all 8 ch) ----
    int goff[R_SL], loff[R_SL];
    #pragma unroll
    for (int q = 0; q < R_SL; ++q){
        int i = (int)threadIdx.x + q*256;
        goff[q] = -1; loff[q] = -1;
        if (q < R_SL-1 || i < R_HN){
            int hr = i / R_HW, hc = i - hr*R_HW;
            loff[q] = hr*R_LS + hc;
            int gr = row0 + hr - 3, gc = col0 + hc - 3;
            if ((unsigned)gr < (unsigned)H_ && (unsigned)gc < (unsigned)W_)
                goff[q] = gr*W_ + gc;
        }
    }

    // ---- stage all 8 channels in one burst ----
    #pragma unroll
    for (int ch = 0; ch < RG_CH; ++ch){
        const float* xc = xg + (size_t)ch*HW_;
        float v[R_SL];
        #pragma unroll
        for (int q = 0; q < R_SL; ++q){
            v[q] = 0.f;
            if (goff[q] >= 0) v[q] = xc[goff[q]];
        }
        #pragma unroll
        for (int q = 0; q < R_SL; ++q)
            if (loff[q] >= 0) tile[ch*R_PL + loff[q]] = v[q];
    }
    __syncthreads();

    // ---- conv: 8 ch x 7x7, 4 output px/thread ----
    float acc[4] = {0.f,0.f,0.f,0.f};
    #pragma unroll
    for (int ch = 0; ch < RG_CH; ++ch){
        const float* wr = wgr + ch*49;           // block-uniform -> SGPR
        const float* tb = &tile[ch*R_PL];
        #pragma unroll
        for (int ky = 0; ky < 7; ++ky){
            const float* trp = &tb[(ty+ky)*R_LS + 4*tx];
            float4 va = *(const float4*)(trp);
            float4 vb = *(const float4*)(trp+4);
            float2 vc = *(const float2*)(trp+8);
            float win[10] = {va.x,va.y,va.z,va.w, vb.x,vb.y,vb.z,vb.w, vc.x,vc.y};
            #pragma unroll
            for (int kx = 0; kx < 7; ++kx){
                float w = wr[ky*7+kx];
                acc[0] += w*win[kx+0];
                acc[1] += w*win[kx+1];
                acc[2] += w*win[kx+2];
                acc[3] += w*win[kx+3];
            }
        }
    }

    if (g == 0){
        float rbv = rb[0];
        acc[0]+=rbv; acc[1]+=rbv; acc[2]+=rbv; acc[3]+=rbv;
    }

    // ---- fused gating dot: pl[e] = sum_px acc[px] * wg[px, e] ----
    const float* wrow = wg + (size_t)(row*W_ + colb)*E_;   // 128B-aligned
    float pl[E_];
    #pragma unroll
    for (int e = 0; e < E_; ++e) pl[e] = 0.f;
    #pragma unroll
    for (int p = 0; p < 4; ++p){
        float4 wa = *(const float4*)(wrow + p*E_);
        float4 wb = *(const float4*)(wrow + p*E_ + 4);
        float a = acc[p];
        pl[0] += a*wa.x; pl[1] += a*wa.y; pl[2] += a*wa.z; pl[3] += a*wa.w;
        pl[4] += a*wb.x; pl[5] += a*wb.y; pl[6] += a*wb.z; pl[7] += a*wb.w;
    }
    #pragma unroll
    for (int off = 32; off > 0; off >>= 1){
        #pragma unroll
        for (int e = 0; e < E_; ++e) pl[e] += __shfl_down(pl[e], off, 64);
    }
    int lane = threadIdx.x & 63, wv = threadIdx.x >> 6;
    if (lane == 0){
        #pragma unroll
        for (int e = 0; e < E_; ++e) pred[wv][e] = pl[e];
    }
    __syncthreads();
    if (threadIdx.x < E_){
        int e = threadIdx.x;
        float s = pred[0][e] + pred[1][e] + pred[2][e] + pred[3][e];
        atomicAdd(&logits[b*E_ + e], s);
    }
}

// ---- k2: parallel top-2 gating + loss (logits already summed) ----
__global__ void k2_gating(const float* __restrict__ logits,
                          int* __restrict__ sel,
                          float* __restrict__ out){
    __shared__ float g1s[B_], g2s[B_];
    __shared__ int   i1s[B_], i2s[B_];
    __shared__ float impS[E_], cntS[E_];
    int t = threadIdx.x;
    if (t < B_){
        const float* l = logits + t*E_;
        int i1 = 0;
        #pragma unroll
        for (int e = 1; e < E_; ++e) if (l[e] > l[i1]) i1 = e;   // ties -> lowest idx
        int i2 = (i1 == 0) ? 1 : 0;
        #pragma unroll
        for (int e = 0; e < E_; ++e) if (e != i1 && l[e] > l[i2]) i2 = e;
        float ex = expf(l[i2] - l[i1]);
        float g1 = 1.f/(1.f+ex), g2 = ex/(1.f+ex);
        sel[t] = i1; sel[B_ + t] = i2;
        g1s[t] = g1; g2s[t] = g2; i1s[t] = i1; i2s[t] = i2;
    }
    __syncthreads();
    if (t < E_){
        float im = 0.f, cn = 0.f;
        #pragma unroll
        for (int bb = 0; bb < B_; ++bb){
            im += (i1s[bb]==t ? g1s[bb] : 0.f) + (i2s[bb]==t ? g2s[bb] : 0.f);
            cn += (i1s[bb]==t ? 1.f : 0.f)     + (i2s[bb]==t ? 1.f : 0.f);
        }
        impS[t] = im; cntS[t] = cn;
    }
    __syncthreads();
    if (t == 0){
        float m1 = 0.f, m2 = 0.f;
        for (int e = 0; e < E_; ++e){ m1 += impS[e]; m2 += cntS[e]; }
        m1 *= (1.f/E_); m2 *= (1.f/E_);
        float v1 = 0.f, v2 = 0.f;
        for (int e = 0; e < E_; ++e){
            float d1 = impS[e] - m1; v1 += d1*d1;
            float d2 = cntS[e] - m2; v2 += d2*d2;
        }
        v1 *= (1.f/(E_-1)); v2 *= (1.f/(E_-1));
        float loss = (v1/(m1*m1 + 1e-10f) + v2/(m2*m2 + 1e-10f)) * 0.01f;
        out[(size_t)B_*HW_*C_] = loss;
    }
}

// ================= k3: tiled experts+shared conv + LSE combine =================
// 16x16 pixel tile, 2 half-blocks of 4 chunks x 8 channels (2048 blocks).
// Staging offsets precomputed once (chunk-invariant spatial pattern).
#define C3_NCH 8
#define C3_CS  28                 // LDS col stride within a row (22 used)
#define C3_CHS 620                // channel plane stride (mod 32 = 12)
#define C3_WST 60                 // weight stride per channel (mod 32 = 28)
#define C3_TN  (C3_NCH*22*22)     // 3872 staged x elements
#define C3_WN  (3*C3_NCH*C3_WST)  // 1440 staged weight slots
#define C3_XS  16                 // x staging slots/thread
#define C3_WS  6                  // weight staging slots/thread

__global__ __launch_bounds__(256) void k3_tiled(const float* __restrict__ x,
                                                const float* __restrict__ ew,
                                                const float* __restrict__ eb,
                                                const float* __restrict__ sw,
                                                const float* __restrict__ sb,
                                                const int* __restrict__ sel,
                                                float* __restrict__ out){
    __shared__ __align__(16) float tile[C3_NCH*C3_CHS];   // 4960 f = 19.84 KB
    __shared__ __align__(16) float wbuf[C3_WN];           // 1440 f =  5.76 KB

    int id = blockIdx.x;
    int half = id & 1; id >>= 1;
    int cx = id & 7; id >>= 3;
    int cy = id & 7; id >>= 3;
    int b  = id;                           // 16  -> 2048 blocks total
    int r0 = cy*16, c0 = cx*16;

    int c8   = threadIdx.x & 7;            // channel within chunk
    int slot = threadIdx.x >> 3;           // 0..31
    int trow = slot >> 1;                  // 0..15
    int colt = (slot & 1) * 8;             // col half: 0 or 8

    int e1 = sel[b], e2 = sel[B_ + b];

    // ---- precompute staging offsets (chunk-invariant) ----
    int xgo[C3_XS], xlo[C3_XS];
    #pragma unroll
    for (int q = 0; q < C3_XS; ++q){
        int i = (int)threadIdx.x + q*256;
        xgo[q] = -1; xlo[q] = -1;
        if (q < C3_XS-1 || i < C3_TN){
            int ci = i / 484; int rem = i - ci*484;
            int hr = rem / 22, hc = rem - hr*22;
            xlo[q] = ci*C3_CHS + hr*C3_CS + hc;
            int gr = r0 + hr - 3, gc = c0 + hc - 3;
            if ((unsigned)gr < (unsigned)H_ && (unsigned)gc < (unsigned)W_)
                xgo[q] = ci*HW_ + gr*W_ + gc;
        }
    }
    int wrel[C3_WS], wsel[C3_WS], wlo[C3_WS];
    #pragma unroll
    for (int q = 0; q < C3_WS; ++q){
        int i = (int)threadIdx.x + q*256;
        wrel[q] = -1; wsel[q] = 0; wlo[q] = -1;
        if (q < C3_WS-1 || i < C3_WN){
            int which = i / (C3_NCH*C3_WST);
            int rem = i - which*(C3_NCH*C3_WST);
            int wc = rem / C3_WST;
            int tt = rem - wc*C3_WST;
            int ky = tt >> 3, kx = tt & 7;
            wlo[q] = i; wsel[q] = which;
            if (ky < 7 && kx < 7) wrel[q] = wc*49 + ky*7 + kx;
        }
    }

    for (int kk = 0; kk < 4; ++kk){
        int cc0 = (half*4 + kk)*C3_NCH;
        __syncthreads();                   // everyone done reading prev chunk
        // stage x via precomputed offsets
        const float* xb = x + (size_t)(b*C_ + cc0)*HW_;
        #pragma unroll
        for (int q = 0; q < C3_XS; ++q){
            if (xlo[q] >= 0){
                float v = 0.f;
                if (xgo[q] >= 0) v = xb[xgo[q]];
                tile[xlo[q]] = v;
            }
        }
        // stage weights via precomputed offsets
        const float* pe1 = ew + (size_t)(e1*C_ + cc0)*49;
        const float* pe2 = ew + (size_t)(e2*C_ + cc0)*49;
        const float* psw = sw + (size_t)cc0*49;
        #pragma unroll
        for (int q = 0; q < C3_WS; ++q){
            if (wlo[q] >= 0){
                float v = 0.f;
                if (wrel[q] >= 0){
                    const float* pw = (wsel[q]==0) ? pe1 : ((wsel[q]==1) ? pe2 : psw);
                    v = pw[wrel[q]];
                }
                wbuf[wlo[q]] = v;
            }
        }
        __syncthreads();

        float a1[8], a2[8], a3[8];
        #pragma unroll
        for (int c = 0; c < 8; ++c){ a1[c]=0.f; a2[c]=0.f; a3[c]=0.f; }

        const float* tb = tile + c8*C3_CHS;
        #pragma unroll
        for (int ky = 0; ky < 7; ++ky){
            const float* trp = tb + (trow+ky)*C3_CS + colt;
            float win[16];
            #pragma unroll
            for (int q = 0; q < 4; ++q){
                float4 v4 = *(const float4*)(trp + 4*q);
                win[4*q+0]=v4.x; win[4*q+1]=v4.y; win[4*q+2]=v4.z; win[4*q+3]=v4.w;
            }
            float u1[7], u2[7], u3[7];
            { const float* wp = wbuf + (0*C3_NCH + c8)*C3_WST + ky*8;
              float4 a = *(const float4*)wp, c4 = *(const float4*)(wp+4);
              u1[0]=a.x;u1[1]=a.y;u1[2]=a.z;u1[3]=a.w;u1[4]=c4.x;u1[5]=c4.y;u1[6]=c4.z; }
            { const float* wp = wbuf + (1*C3_NCH + c8)*C3_WST + ky*8;
              float4 a = *(const float4*)wp, c4 = *(const float4*)(wp+4);
              u2[0]=a.x;u2[1]=a.y;u2[2]=a.z;u2[3]=a.w;u2[4]=c4.x;u2[5]=c4.y;u2[6]=c4.z; }
            { const float* wp = wbuf + (2*C3_NCH + c8)*C3_WST + ky*8;
              float4 a = *(const float4*)wp, c4 = *(const float4*)(wp+4);
              u3[0]=a.x;u3[1]=a.y;u3[2]=a.z;u3[3]=a.w;u3[4]=c4.x;u3[5]=c4.y;u3[6]=c4.z; }

            #pragma unroll
            for (int c = 0; c < 8; ++c){
                #pragma unroll
                for (int kx = 0; kx < 7; ++kx){
                    float xv = win[c+kx];
                    a1[c] += u1[kx]*xv;
                    a2[c] += u2[kx]*xv;
                    a3[c] += u3[kx]*xv;
                }
            }
        }

        float b1 = eb[e1*C_ + cc0 + c8];
        float b2 = eb[e2*C_ + cc0 + c8];
        float b3 = sb[cc0 + c8];
        size_t obase = ((size_t)b*HW_ + (size_t)(r0+trow)*W_ + (c0+colt))*C_ + cc0 + c8;
        #pragma unroll
        for (int c = 0; c < 8; ++c){
            float o1 = a1[c] + b1;
            float o2 = a2[c] + b2;
            float o3 = a3[c] + b3;
            float v = __expf(o1) + __expf(o2);
            if (v == 0.f) v = 2.220446049250313e-16f;
            out[obase + (size_t)c*C_] = __logf(v) + o3;
        }
    }
}

extern "C" void kernel_launch(void* const* d_in, const int* in_sizes, int n_in,
                              void* d_out, int out_size, void* d_ws, size_t ws_size,
                              hipStream_t stream) {
    float* out = (float*)d_out;

    // ---- host-side assumption assertions -> sentinel in absmax ----
    static const int exp_sizes[8] = {16777216, 3136, 1, 131072, 25088, 512, 3136, 64};
    if (n_in != 8){ k_sentinel<<<1,64,0,stream>>>(out, 500.f); return; }
    for (int i = 0; i < 8; ++i){
        if (in_sizes[i] != exp_sizes[i]){
            k_sentinel<<<1,64,0,stream>>>(out, 600.f + 8.f*i); return;
        }
    }
    if (out_size != 16777217){ k_sentinel<<<1,64,0,stream>>>(out, 800.f); return; }
    if (ws_size < (size_t)(WS_SEL + 64)*4){ k_sentinel<<<1,64,0,stream>>>(out, 900.f); return; }

    const float* x  = (const float*)d_in[0];
    const float* rw = (const float*)d_in[1];
    const float* rb = (const float*)d_in[2];
    const float* wg = (const float*)d_in[3];
    const float* ew = (const float*)d_in[4];
    const float* eb = (const float*)d_in[5];
    const float* sw = (const float*)d_in[6];
    const float* sb = (const float*)d_in[7];
    float* wsf = (float*)d_ws;

    hipMemsetAsync(wsf + WS_LOGITS, 0, (B_*E_)*sizeof(float), stream);
    k1p<<<2048, 256, 0, stream>>>(x, rw, rb, wg, wsf + WS_LOGITS);
    k2_gating<<<1, 64, 0, stream>>>(wsf + WS_LOGITS, (int*)(wsf + WS_SEL), out);
    k3_tiled<<<2048, 256, 0, stream>>>(x, ew, eb, sw, sb,
                                       (const int*)(wsf + WS_SEL), out);
}